// Round 1
// baseline (4231.684 us; speedup 1.0000x reference)
//
#include <hip/hip_runtime.h>
#include <cstdint>

#define TT 128   // time steps (= bucket_size)
#define BB 128   // batch
#define II 512   // input dim
#define HH 512   // hidden dim
#define DD 1024  // I + H
#define NC 513   // H + 1
#define NPAD 520 // row pitch for lnXW / vbuf (bf16)
#define NT 36    // n-tiles of 16 in GEMM (576 padded cols)
#define EPSL 1e-5f

typedef short  s8v  __attribute__((ext_vector_type(8)));
typedef float  f4v  __attribute__((ext_vector_type(4)));

__device__ __forceinline__ ushort f2bf(float f){
  uint u = __builtin_bit_cast(uint, f);
  uint r = (u + 0x7fffu + ((u >> 16) & 1u)) >> 16;
  return (ushort)r;
}
__device__ __forceinline__ float bf2f(ushort s){
  uint u = ((uint)s) << 16;
  return __builtin_bit_cast(float, u);
}
__device__ __forceinline__ float hsig(float x){
  return fminf(fmaxf(0.2f * x + 0.5f, 0.f), 1.f);
}

// ---------------- pre-pack W / U into MFMA B-fragment order ----------------
// dst element idx = ((kc*NT + nt)*16 + ni)*8 + kl  holds  src[k=kc*8+kl][n=nt*16+ni]
__global__ void prepack_B(const float* __restrict__ src, ushort* __restrict__ dst){
  int idx = blockIdx.x * 256 + threadIdx.x;
  if (idx >= 128 * NT * 16 * 8) return;
  int kl = idx & 7;
  int ni = (idx >> 3) & 15;
  int nt = (idx >> 7) % NT;
  int kc = idx / (NT * 16 * 8);
  int k = kc * 8 + kl;
  int n = nt * 16 + ni;
  float v = (n < NC) ? src[k * NC + n] : 0.f;
  dst[idx] = f2bf(v);
}

// ---------------- pre-pack U_hi (rows I..I+511) for the recurrence GEMV ----
// Upk4 uint idx = (kpg*512 + n)*4 + j  holds bf16 pair (U[I+8kpg+2j][n], U[I+8kpg+2j+1][n])
__global__ void prepack_Uhi(const float* __restrict__ U, uint* __restrict__ Upk4,
                            ushort* __restrict__ ucol){
  int idx = blockIdx.x * 256 + threadIdx.x;
  if (idx < 64 * 512 * 4){
    int j   = idx & 3;
    int n   = (idx >> 2) & 511;
    int kpg = idx >> 11;
    int k0  = II + 8 * kpg + 2 * j;
    ushort lo = f2bf(U[(size_t)k0 * NC + n]);
    ushort hi = f2bf(U[(size_t)(k0 + 1) * NC + n]);
    Upk4[idx] = (uint)lo | ((uint)hi << 16);
  }
  if (idx < 512) ucol[idx] = f2bf(U[(size_t)(II + idx) * NC + (NC - 1)]);
}

// ---------------- fused GEMM (+ optional row-LayerNorm) -------------------
// out[r][n] = do_ln ? g[n]*((A@B - m)/(std+eps)) + bet[n] + bias[n] : A@B   (bf16)
// A: fp32. amode 0: A[r][k] = x[(b*TT+t)*II + k] with r = t*BB+b (K=512)
//          amode 1: A[r][k] = h_seq[r*DD + k]                     (K=1024)
__global__ __launch_bounds__(1024) void gemm_ln(
    const float* __restrict__ A, int amode, int ksteps,
    const ushort* __restrict__ Bpk, ushort* __restrict__ out,
    int do_ln, const float* __restrict__ gam, const float* __restrict__ bet,
    const float* __restrict__ bias)
{
  __shared__ ushort As[64][40];
  __shared__ float red[4][4][16][2];
  int tid = threadIdx.x;
  int lane = tid & 63, wid = tid >> 6;
  int quad = lane >> 4, l16 = lane & 15;
  int wm = wid >> 2, wn = wid & 3;
  int blk = blockIdx.x;

  f4v acc[9];
#pragma unroll
  for (int i = 0; i < 9; i++) acc[i] = (f4v){0.f, 0.f, 0.f, 0.f};

  int arow = tid >> 4;
  int acp  = tid & 15;
  int r = blk * 64 + arow;
  const float* aptr;
  if (amode == 0){ int t = r >> 7, b = r & 127; aptr = A + ((size_t)(b * TT + t)) * II + acp * 2; }
  else           { aptr = A + (size_t)r * DD + acp * 2; }

  for (int ks = 0; ks < ksteps; ks++){
    __syncthreads();
    float2 a2 = *(const float2*)(aptr + ks * 32);
    uint pk = (uint)f2bf(a2.x) | ((uint)f2bf(a2.y) << 16);
    *(uint*)&As[arow][acp * 2] = pk;
    __syncthreads();
    s8v af = *(const s8v*)&As[wm * 16 + l16][quad * 8];
    int kc = ks * 4 + quad;
    const s8v* bp = (const s8v*)Bpk + (size_t)kc * (NT * 16) + l16;
#pragma unroll
    for (int i = 0; i < 9; i++){
      s8v bf = bp[(wn * 9 + i) * 16];
      acc[i] = __builtin_amdgcn_mfma_f32_16x16x32_bf16(af, bf, acc[i], 0, 0, 0);
    }
  }

  int rowbase = blk * 64 + wm * 16 + quad * 4;
  if (do_ln){
    float s1[4], s2[4];
#pragma unroll
    for (int g = 0; g < 4; g++){
      float a = 0.f, q = 0.f;
#pragma unroll
      for (int i = 0; i < 9; i++){ float v = acc[i][g]; a += v; q += v * v; }
#pragma unroll
      for (int m = 1; m < 16; m <<= 1){ a += __shfl_xor(a, m, 64); q += __shfl_xor(q, m, 64); }
      s1[g] = a; s2[g] = q;
    }
    if (l16 == 0){
#pragma unroll
      for (int g = 0; g < 4; g++){
        red[wm][wn][quad * 4 + g][0] = s1[g];
        red[wm][wn][quad * 4 + g][1] = s2[g];
      }
    }
    __syncthreads();
#pragma unroll
    for (int g = 0; g < 4; g++){
      int rr = quad * 4 + g;
      float S1 = red[wm][0][rr][0] + red[wm][1][rr][0] + red[wm][2][rr][0] + red[wm][3][rr][0];
      float S2 = red[wm][0][rr][1] + red[wm][1][rr][1] + red[wm][2][rr][1] + red[wm][3][rr][1];
      float mean = S1 * (1.f / 513.f);
      float var  = S2 * (1.f / 513.f) - mean * mean;
      float inv  = 1.f / (sqrtf(var + EPSL) + EPSL);
      size_t rg = (size_t)(rowbase + g);
#pragma unroll
      for (int i = 0; i < 9; i++){
        int n = wn * 144 + i * 16 + l16;
        if (n < NC){
          float val = gam[n] * ((acc[i][g] - mean) * inv) + bet[n] + bias[n];
          out[rg * NPAD + n] = f2bf(val);
        }
      }
    }
  } else {
#pragma unroll
    for (int g = 0; g < 4; g++){
      size_t rg = (size_t)(rowbase + g);
#pragma unroll
      for (int i = 0; i < 9; i++){
        int n = wn * 144 + i * 16 + l16;
        if (n < NC) out[rg * NPAD + n] = f2bf(acc[i][g]);
      }
    }
  }
}

// ---------------- per-batch-row sequential recurrence ----------------------
// one block per batch row b; 512 threads; thread n owns column n (thread 0 also col 512)
__global__ __launch_bounds__(512) void rnn_layer(
    int layer,
    const float* __restrict__ x,
    float* __restrict__ h_seq,
    const ushort* __restrict__ lnXW,
    ushort* __restrict__ vbuf,
    float* __restrict__ fkbuf,
    float* __restrict__ hvbuf,
    const uint* __restrict__ Upk4,
    const ushort* __restrict__ ucol,
    const int* __restrict__ mask,
    const float* __restrict__ gam1, const float* __restrict__ bet1,
    const float* __restrict__ bias,
    float* __restrict__ out)
{
  __shared__ __align__(16) float v[NC];
  __shared__ __align__(16) float tanhv[512];
  __shared__ float red[16];
  __shared__ float shs[12]; // 0:mean 1:inv 2:s0 3:sum20 4:h_only 5:x_only 6:both 8:fk_c 9:hv_c
  int tid = threadIdx.x;
  int b = blockIdx.x;
  int lane = tid & 63, wid = tid >> 6;

  v[tid] = 0.f;
  if (tid == 0){ v[512] = 0.f; shs[8] = 0.f; shs[9] = 0.f; }
  float h_lo = 0.f, h_hi = 0.f;
  float g1n = gam1[tid], b1n = bet1[tid];
  __syncthreads();

  for (int t = 0; t < TT; t++){
    bool mk  = mask[b * TT + t] > 0;
    bool mk2 = (t > 0) && (mask[b * TT + t - 1] > 0) && !mk;
    size_t row = (size_t)(t * BB + b);

    // P1: LN stats of v (= h_{t-1} @ U)
    float sv = v[tid];
    float a = sv, q = sv * sv;
    if (tid == 0){ float e = v[512]; a += e; q += e * e; }
#pragma unroll
    for (int m = 1; m < 64; m <<= 1){ a += __shfl_xor(a, m, 64); q += __shfl_xor(q, m, 64); }
    if (lane == 0){ red[wid] = a; red[8 + wid] = q; }
    __syncthreads();
    if (tid == 0){
      float S = 0.f, Q = 0.f;
#pragma unroll
      for (int w = 0; w < 8; w++){ S += red[w]; Q += red[8 + w]; }
      float mean = S * (1.f / 513.f);
      float var  = Q * (1.f / 513.f) - mean * mean;
      shs[0] = mean; shs[1] = 1.f / (sqrtf(var + EPSL) + EPSL);
    }
    __syncthreads();
    float mean = shs[0], inv = shs[1];

    // P2: s = lnXW + LN(v); tanh for cols 1..512
    {
      float sum2 = (v[tid] - mean) * inv * g1n + b1n;
      float s = bf2f(lnXW[row * NPAD + tid]) + sum2;
      if (tid == 0){
        shs[2] = s; shs[3] = sum2;
        float sum2e = (v[512] - mean) * inv * gam1[512] + bet1[512];
        float se = bf2f(lnXW[row * NPAD + 512]) + sum2e;
        tanhv[511] = tanhf(se);
      } else {
        tanhv[tid - 1] = tanhf(s);
      }
    }
    __syncthreads();

    // P2.5: scalar gate math (thread 0)
    if (tid == 0){
      float fkp_tm1, fkp, hvp;
      if (layer == 0){ fkp_tm1 = 0.f; fkp = 0.f; hvp = 1.f; }
      else {
        fkp_tm1 = fkbuf[t * BB + b];
        fkp = (t + 1 < TT) ? fkbuf[(t + 1) * BB + b] : 0.f;
        hvp = hvbuf[t * BB + b];
      }
      float fk_c = shs[8], hv_c = shs[9];
      float fk_both = hsig(shs[2]);
      float fk_t1 = hsig(shs[3] + bias[0]);
      float fk = fkp_tm1 + (1.f - fkp_tm1) * (fk_c * fk_both + (1.f - fk_c) * fk_t1);
      if (mk2) fk = 0.f;
      float h_only = hv_c * fk * (fkp + (1.f - fkp) * (1.f - hvp));
      float x_only = hvp * (1.f - fkp) * (1.f - fk + fk * (1.f - hv_c));
      float both = (1.f - fkp) * fk * hv_c * hvp;
      float hv = 1.f - (1.f - h_only) * (1.f - x_only) * (1.f - both);
      float fk_new = mk ? fk : fk_c;
      float hv_new = mk ? hv : hv_c;
      if (mk2) fk_new = 0.f;
      shs[4] = h_only; shs[5] = x_only; shs[6] = both;
      shs[8] = fk_new; shs[9] = hv_new;
      fkbuf[t * BB + b] = fk_new; hvbuf[t * BB + b] = hv_new;
    }
    __syncthreads();

    // P3: GEMV y[n] = tanh . U_hi[:, n]   (thread n = tid, cols 0..511)
    float y0 = 0.f, y1 = 0.f, y2 = 0.f, y3 = 0.f;
    const uint* up = Upk4 + tid * 4;
    for (int kpg = 0; kpg < 64; kpg++){
      uint4 uu = *(const uint4*)(up + (size_t)kpg * 2048);
      float4 ta = *(const float4*)&tanhv[8 * kpg];
      float4 tb = *(const float4*)&tanhv[8 * kpg + 4];
      y0 = fmaf(bf2f((ushort)(uu.x & 0xffffu)), ta.x, y0);
      y0 = fmaf(bf2f((ushort)(uu.x >> 16)),     ta.y, y0);
      y1 = fmaf(bf2f((ushort)(uu.y & 0xffffu)), ta.z, y1);
      y1 = fmaf(bf2f((ushort)(uu.y >> 16)),     ta.w, y1);
      y2 = fmaf(bf2f((ushort)(uu.z & 0xffffu)), tb.x, y2);
      y2 = fmaf(bf2f((ushort)(uu.z >> 16)),     tb.y, y2);
      y3 = fmaf(bf2f((ushort)(uu.w & 0xffffu)), tb.z, y3);
      y3 = fmaf(bf2f((ushort)(uu.w >> 16)),     tb.w, y3);
    }
    float y = (y0 + y1) + (y2 + y3);
    // col 512 via block reduction
    float p512 = tanhv[tid] * bf2f(ucol[tid]);
#pragma unroll
    for (int m = 1; m < 64; m <<= 1) p512 += __shfl_xor(p512, m, 64);
    if (lane == 0) red[wid] = p512;
    __syncthreads();

    // P4: update h, v; write streams
    float h_only = shs[4], x_only = shs[5], both = shs[6];
    float xlo, xhi;
    if (layer == 0){ xlo = x[((size_t)(b * TT + t)) * II + tid]; xhi = 0.f; }
    else { xlo = h_seq[row * DD + tid]; xhi = h_seq[row * DD + 512 + tid]; }
    float th = tanhv[tid];
    float nh_lo = h_only * h_lo + x_only * xlo;
    float nh_hi = h_only * h_hi + x_only * xhi + both * th;
    if (mk){ h_lo = nh_lo; h_hi = nh_hi; }

    float xu = bf2f(vbuf[row * NPAD + tid]);
    float nv = h_only * v[tid] + x_only * xu + both * y;
    if (mk) v[tid] = nv;
    vbuf[row * NPAD + tid] = f2bf(v[tid]);
    if (tid == 0){
      float y512 = 0.f;
#pragma unroll
      for (int w = 0; w < 8; w++) y512 += red[w];
      float xu5 = bf2f(vbuf[row * NPAD + 512]);
      float nv5 = h_only * v[512] + x_only * xu5 + both * y512;
      if (mk) v[512] = nv5;
      vbuf[row * NPAD + 512] = f2bf(v[512]);
    }
    h_seq[row * DD + tid] = h_lo;
    h_seq[row * DD + 512 + tid] = h_hi;
    if (layer == 3 && t == TT - 1) out[b * HH + tid] = h_hi;
    __syncthreads();
  }
}

extern "C" void kernel_launch(void* const* d_in, const int* in_sizes, int n_in,
                              void* d_out, int out_size, void* d_ws, size_t ws_size,
                              hipStream_t stream)
{
  (void)in_sizes; (void)n_in; (void)out_size; (void)ws_size;
  const float* x      = (const float*)d_in[0];
  const int*   mask   = (const int*)d_in[1];
  const float* W      = (const float*)d_in[2];
  const float* U      = (const float*)d_in[3];
  const float* bias   = (const float*)d_in[4];
  const float* gammas = (const float*)d_in[5];
  const float* betas  = (const float*)d_in[6];
  float* out = (float*)d_out;

  char* ws = (char*)d_ws;
  size_t off = 0;
  auto alloc = [&](size_t bytes) -> void* {
    void* p = ws + off;
    off += (bytes + 255) & ~(size_t)255;
    return p;
  };
  float*  h_seq = (float*) alloc((size_t)TT * BB * DD * 4);
  ushort* lnXW  = (ushort*)alloc((size_t)TT * BB * NPAD * 2);
  ushort* vbuf  = (ushort*)alloc((size_t)TT * BB * NPAD * 2);
  float*  fkbuf = (float*) alloc((size_t)TT * BB * 4);
  float*  hvbuf = (float*) alloc((size_t)TT * BB * 4);
  ushort* Wpk   = (ushort*)alloc((size_t)128 * NT * 16 * 8 * 2);
  ushort* Upk   = (ushort*)alloc((size_t)128 * NT * 16 * 8 * 2);
  uint*   Upk4  = (uint*)  alloc((size_t)64 * 512 * 4 * 4);
  ushort* ucol  = (ushort*)alloc(512 * 2);

  int npk = 128 * NT * 16 * 8;
  prepack_B<<<dim3((npk + 255) / 256), dim3(256), 0, stream>>>(W, Wpk);
  prepack_B<<<dim3((npk + 255) / 256), dim3(256), 0, stream>>>(U, Upk);
  prepack_Uhi<<<dim3((64 * 512 * 4 + 255) / 256), dim3(256), 0, stream>>>(U, Upk4, ucol);

  const float* g0 = gammas,      *g1 = gammas + NC;
  const float* be0 = betas,      *be1 = betas + NC;

  // layer 0: lnXW = LN(x @ W_lo)+b ; vbuf = x @ U_lo (raw)
  gemm_ln<<<dim3(256), dim3(1024), 0, stream>>>(x, 0, 16, Wpk, lnXW, 1, g0, be0, bias);
  gemm_ln<<<dim3(256), dim3(1024), 0, stream>>>(x, 0, 16, Upk, vbuf, 0, g0, be0, bias);
  rnn_layer<<<dim3(BB), dim3(512), 0, stream>>>(0, x, h_seq, lnXW, vbuf, fkbuf, hvbuf,
                                                Upk4, ucol, mask, g1, be1, bias, out);
  for (int d = 1; d < 4; d++){
    gemm_ln<<<dim3(256), dim3(1024), 0, stream>>>(h_seq, 1, 32, Wpk, lnXW, 1, g0, be0, bias);
    rnn_layer<<<dim3(BB), dim3(512), 0, stream>>>(d, x, h_seq, lnXW, vbuf, fkbuf, hvbuf,
                                                  Upk4, ucol, mask, g1, be1, bias, out);
  }
}